// Round 6
// baseline (382.742 us; speedup 1.0000x reference)
//
#include <hip/hip_runtime.h>
#include <hip/hip_bf16.h>
#include <stdint.h>
#include <stddef.h>

// ---------------------------------------------------------------------------
// MultiHeadAttention: q/k/v = X @ W.T + b ; flash-attn per head ; out @ Wo.T+bo
// FP32 in/out buffers; bf16 MFMA internally.
// B=4 S=2048 D=1024 H=16 Dh=64 -> M = B*S = 8192
// Round 11: gemm_proj occupancy attack. r10 was latency-bound at 12 waves/CU
// (MfmaUtil 17.6% == 425/2495 TF; acc64+prefetch regs ~140 -> 3 waves/SIMD).
// Same 128x128 tile now runs 512 thr / 8 waves: wave owns 32x64 (acc 32 regs),
// A-stage 8 f32/thread, W-stage 1 async chunk/thread -> ~100 regs ->
// launch_bounds(512,4) (cap 128) -> 2 blocks x 8 waves = 16 waves/CU (50%).
// Counted-vmcnt pipeline kept: A(kt+2) regs fly across the barrier (vmcnt(2)),
// W(kt+1) async staged under the MFMA cluster.
// attn / gemm_out / conv_w unchanged from round 10.
// ---------------------------------------------------------------------------

typedef __bf16 bf16_t;
typedef __bf16 bf16x4 __attribute__((ext_vector_type(4)));
typedef __bf16 bf16x8 __attribute__((ext_vector_type(8)));
typedef float f32x4 __attribute__((ext_vector_type(4)));

#define D_MODEL 1024
#define M_ROWS  8192
#define S_LEN   2048
#define N_HEADS 16
#define HEAD_DIM 64
#define GBK 32
#define NT (D_MODEL / GBK)   // 32 k-tiles

__device__ __forceinline__ void async_copy16(void* lds, const void* g) {
    __builtin_amdgcn_global_load_lds(
        (const __attribute__((address_space(1))) void*)g,
        (__attribute__((address_space(3))) void*)lds, 16, 0, 0);
}

__device__ __forceinline__ uint32_t cvt_pk_bf16(float lo, float hi) {
    uint32_t r;
    asm("v_cvt_pk_bf16_f32 %0, %1, %2" : "=v"(r) : "v"(lo), "v"(hi));
    return r;
}

// ---------------------------------------------------------------------------
// fp32 -> bf16 conversion (W matrices, 1M elems each). grid (512, nmat).
// ---------------------------------------------------------------------------
__global__ __launch_bounds__(256) void conv_w(
    const float* __restrict__ s0, const float* __restrict__ s1, const float* __restrict__ s2,
    bf16_t* __restrict__ d0, bf16_t* __restrict__ d1, bf16_t* __restrict__ d2)
{
    const float* s; bf16_t* d;
    if (blockIdx.y == 0)      { s = s0; d = d0; }
    else if (blockIdx.y == 1) { s = s1; d = d1; }
    else                      { s = s2; d = d2; }
    const int i = (blockIdx.x * 256 + threadIdx.x) * 8;
    const f32x4 a = *(const f32x4*)(s + i);
    const f32x4 b = *(const f32x4*)(s + i + 4);
    bf16x8 o;
#pragma unroll
    for (int j = 0; j < 4; j++) { o[j] = (bf16_t)a[j]; o[4 + j] = (bf16_t)b[j]; }
    *(bf16x8*)(d + i) = o;
}

// ---------------------------------------------------------------------------
// Projection GEMM: C[m,n] = sum_k A[m,k]*W[n,k] + bias[n]
// A fp32 (reg-staged, 2-deep, loads LIVE ACROSS the barrier via vmcnt(2));
// W bf16 (global_load_lds, staged under the MFMA cluster); bias fp32; C bf16.
// 128x128 tile, BK=32, 512 thr = 8 waves of 32x64 (4m x 2n grid).
// Raw s_barrier + counted vmcnt per k-step. XCD-chunked swizzle.
// z==0 (Q): output scaled 0.125. z==1 (K): scaled log2e. z==2 (V): transposed
// per head [b][dh][s] with per-32-key permutation.
// ---------------------------------------------------------------------------
__global__ __launch_bounds__(512, 4) void gemm_proj(
    const float* __restrict__ A0, const bf16_t* __restrict__ W0, const float* __restrict__ b0,
    const float* __restrict__ A1, const bf16_t* __restrict__ W1, const float* __restrict__ b1,
    const float* __restrict__ A2, const bf16_t* __restrict__ W2, const float* __restrict__ b2,
    bf16_t* C0, bf16_t* C1, bf16_t* C2)
{
    const int lin = blockIdx.x + ((int)blockIdx.y << 3) + ((int)blockIdx.z << 9);
    const int nl  = (lin & 7) * 192 + (lin >> 3);          // bijective, 1536%8==0
    const int z   = nl >> 9;
    const int rem = nl & 511;
    const int bm0 = (rem >> 3) * 128;
    const int bn0 = (rem & 7) * 128;

    const float* A; const bf16_t* W; const float* bias; bf16_t* C;
    if (z == 0)      { A = A0; W = W0; bias = b0; C = C0; }
    else if (z == 1) { A = A1; W = W1; bias = b1; C = C1; }
    else             { A = A2; W = W2; bias = b2; C = C2; }
    const float cs = (z == 0) ? 0.125f : (z == 1) ? 1.4426950408889634f : 1.0f;

    __align__(16) __shared__ bf16_t sA[2][128 * 36];   // padded rows (72B stride)
    __align__(16) __shared__ bf16_t sW[2][128 * GBK];  // linear: async dest

    const int t    = threadIdx.x;
    const int lane = t & 63;
    const int w    = t >> 6;                  // 0..7
    const int wm   = (w & 3) * 32;            // 4 m-slots
    const int wn   = (w >> 2) * 64;           // 2 n-slots
    const int q4   = lane >> 4;
    const int l16  = lane & 15;

    // A staging: row = t>>2 (0..127), chunk = t&3 (8 f32 per thread)
    const int srow = t >> 2;
    const int achk = t & 3;
    const float* aptr = &A[(size_t)(bm0 + srow) * D_MODEL + achk * 8];

    // W staging: 512 chunks, 1/thread; source swizzle cg = cl ^ ((row>>1)&3)
    auto stageW = [&](int buf, int kt) {
        const int row = t >> 2;
        const int cg  = (t & 3) ^ ((row >> 1) & 3);
        async_copy16(&sW[buf][t * 8],
                     &W[(size_t)(bn0 + row) * D_MODEL + kt * GBK + cg * 8]);
    };
    // A LDS write: one bf16x8 at slot achk ^ (srow&3) (72B row stride)
    auto writeA = [&](int buf, f32x4& a0, f32x4& a1) {
        bf16x8 v;
#pragma unroll
        for (int j = 0; j < 4; j++) { v[j] = (bf16_t)a0[j]; v[4 + j] = (bf16_t)a1[j]; }
        const int slot = achk ^ (srow & 3);
        *(bf16x8*)&sA[buf][srow * 36 + slot * 8] = v;
    };

    // preamble: W(0) async; A(0)->arA, A(1)->arB; sA[0] <- arA; publish.
    stageW(0, 0);
    f32x4 arA0 = *(const f32x4*)(aptr);
    f32x4 arA1 = *(const f32x4*)(aptr + 4);
    f32x4 arB0 = *(const f32x4*)(aptr + GBK);
    f32x4 arB1 = *(const f32x4*)(aptr + GBK + 4);
    writeA(0, arA0, arA1);   // compiler waits arA; arB stays in flight
    asm volatile("s_waitcnt vmcnt(2) lgkmcnt(0)" ::: "memory");  // W(0) home
    __builtin_amdgcn_s_barrier();
    __builtin_amdgcn_sched_barrier(0);

    f32x4 acc[2][4];
    const f32x4 zero4 = {0.f, 0.f, 0.f, 0.f};
#pragma unroll
    for (int i = 0; i < 2; i++)
#pragma unroll
        for (int j = 0; j < 4; j++) acc[i][j] = zero4;

    // body(kt): compute buf; stage W(kt+1); load A(kt+2)->arNext;
    // write arCur=A(kt+1) -> sA[buf^1] after the MFMAs.
    auto body = [&](int kt, int buf, f32x4& c0, f32x4& c1, f32x4& n0, f32x4& n1) {
        if (kt + 1 < NT) stageW(buf ^ 1, kt + 1);            // 1 vm
        if (kt + 2 < NT) {
            const float* ap = aptr + (size_t)(kt + 2) * GBK;
            n0 = *(const f32x4*)(ap);
            n1 = *(const f32x4*)(ap + 4);                    // 2 vm
        }

        bf16x8 af[2], bfr[4];
#pragma unroll
        for (int i = 0; i < 2; i++) {
            const int m = wm + i * 16 + l16;
            af[i]  = *(const bf16x8*)&sA[buf][m * 36 + (q4 ^ (m & 3)) * 8];
        }
#pragma unroll
        for (int j = 0; j < 4; j++) {
            const int n = wn + j * 16 + l16;
            bfr[j] = *(const bf16x8*)&sW[buf][n * GBK + (q4 ^ ((n >> 1) & 3)) * 8];
        }
#pragma unroll
        for (int i = 0; i < 2; i++)
#pragma unroll
            for (int j = 0; j < 4; j++)
                acc[i][j] = __builtin_amdgcn_mfma_f32_16x16x32_bf16(af[i], bfr[j], acc[i][j], 0, 0, 0);

        __builtin_amdgcn_sched_barrier(0);
        if (kt + 1 < NT) writeA(buf ^ 1, c0, c1);
        // drain W(kt+1) + LDS writes; keep arNext (2 loads) in flight
        if (kt + 2 < NT) asm volatile("s_waitcnt vmcnt(2) lgkmcnt(0)" ::: "memory");
        else             asm volatile("s_waitcnt vmcnt(0) lgkmcnt(0)" ::: "memory");
        __builtin_amdgcn_s_barrier();
        __builtin_amdgcn_sched_barrier(0);
    };

    for (int kt = 0; kt < NT; kt += 2) {
        body(kt,     0, arB0, arB1, arA0, arA1);
        body(kt + 1, 1, arA0, arA1, arB0, arB1);
    }

    if (z != 2) {
#pragma unroll
        for (int j = 0; j < 4; j++) {
            const int col = bn0 + wn + j * 16 + l16;
            const float bj = bias[col];
#pragma unroll
            for (int i = 0; i < 2; i++) {
                const int rowb = bm0 + wm + i * 16 + q4 * 4;
#pragma unroll
                for (int r = 0; r < 4; r++)
                    C[(size_t)(rowb + r) * D_MODEL + col] = (bf16_t)((acc[i][j][r] + bj) * cs);
            }
        }
    } else {
        const int bb = bm0 >> 11;          // batch (tile never straddles)
        const int sbase = (bm0 & 2047) + wm;
#pragma unroll
        for (int j = 0; j < 4; j++) {
            const int col = bn0 + wn + j * 16 + l16;
            const float bj = bias[col];
            bf16_t* ct = C + ((size_t)bb * 1024 + col) * 2048;
#pragma unroll
            for (int i = 0; i < 2; i++) {
                const int s0 = sbase + i * 16 + q4 * 4;
                // permute: c*32 + g*16 + p*4  ->  c*32 + p*8 + g*4
                const int s0p = (s0 & ~31) | (((s0 >> 2) & 3) << 3) | (((s0 >> 4) & 1) << 2);
                bf16x4 v4;
#pragma unroll
                for (int r = 0; r < 4; r++) v4[r] = (bf16_t)(acc[i][j][r] + bj);
                *(bf16x4*)&ct[s0p] = v4;
            }
        }
    }
}

// ---------------------------------------------------------------------------
// Output GEMM: A bf16 (attention out), W bf16 (pre-converted Wo), bias fp32,
// C fp32 (d_out). BOTH operands via global_load_lds, double-buffered, one
// barrier per iteration, XCD-chunked swizzle. ((row>>1)&3) swizzle:
// conflict-free fragment reads.
// ---------------------------------------------------------------------------
__global__ __launch_bounds__(256, 3) void gemm_out(
    const bf16_t* __restrict__ A, const bf16_t* __restrict__ W,
    const float* __restrict__ bias, float* __restrict__ C)
{
    const int lin = blockIdx.x + ((int)blockIdx.y << 3);
    const int nl  = (lin & 7) * 64 + (lin >> 3);           // bijective, 512%8==0
    const int bm0 = (nl >> 3) * 128;
    const int bn0 = (nl & 7) * 128;

    __align__(16) __shared__ bf16_t sA[2][128 * GBK];
    __align__(16) __shared__ bf16_t sW[2][128 * GBK];

    const int t    = threadIdx.x;
    const int lane = t & 63;
    const int w    = t >> 6;
    const int wm   = (w & 1) * 64;
    const int wn   = (w >> 1) * 64;
    const int q4   = lane >> 4;
    const int l16  = lane & 15;

    auto stage = [&](int buf, int kt) {
#pragma unroll
        for (int i = 0; i < 2; i++) {
            const int cid = i * 256 + t;
            const int row = cid >> 2;
            const int cg  = (cid & 3) ^ ((row >> 1) & 3);
            async_copy16(&sA[buf][cid * 8],
                         &A[(size_t)(bm0 + row) * D_MODEL + kt * GBK + cg * 8]);
            async_copy16(&sW[buf][cid * 8],
                         &W[(size_t)(bn0 + row) * D_MODEL + kt * GBK + cg * 8]);
        }
    };

    stage(0, 0);

    f32x4 acc[4][4];
    const f32x4 zero4 = {0.f, 0.f, 0.f, 0.f};
#pragma unroll
    for (int i = 0; i < 4; i++)
#pragma unroll
        for (int j = 0; j < 4; j++) acc[i][j] = zero4;

    for (int kt = 0; kt < NT; ++kt) {
        const int buf = kt & 1;
        __syncthreads();   // drains async(kt)
        if (kt + 1 < NT) stage(buf ^ 1, kt + 1);

        bf16x8 af[4], bfr[4];
#pragma unroll
        for (int i = 0; i < 4; i++) {
            const int m = wm + i * 16 + l16;
            af[i]  = *(const bf16x8*)&sA[buf][m * GBK + (q4 ^ ((m >> 1) & 3)) * 8];
            const int n = wn + i * 16 + l16;
            bfr[i] = *(const bf16x8*)&sW[buf][n * GBK + (q4 ^ ((n >> 1) & 3)) * 8];
        }
#pragma unroll
        for (int i = 0; i < 4; i++)
#pragma unroll
            for (int j = 0; j < 4; j++)
                acc[i][j] = __builtin_amdgcn_mfma_f32_16x16x32_bf16(af[i], bfr[j], acc[i][j], 0, 0, 0);
    }

#pragma unroll
    for (int j = 0; j < 4; j++) {
        const int col = bn0 + wn + j * 16 + l16;
        const float bj = bias[col];
#pragma unroll
        for (int i = 0; i < 4; i++) {
            const int rowb = bm0 + wm + i * 16 + q4 * 4;
#pragma unroll
            for (int r = 0; r < 4; r++)
                C[(size_t)(rowb + r) * D_MODEL + col] = acc[i][j][r] + bj;
        }
    }
}

// ---------------------------------------------------------------------------
// Flash attention (unchanged from round 9). grid = (B*H=64, S/256=8), 512 thr
// = 8 waves. Double-buffered K / permuted V^T, one raw s_barrier + vmcnt(0)
// per tile. Swapped QK^T (qb pre-scaled 0.125, kb pre-scaled log2e); P via
// v_cvt_pk_bf16_f32 straight into PV A-fragments; row sums via ones-MFMA.
// ---------------------------------------------------------------------------
#define KVT (S_LEN / 128)   // 16 key tiles

__global__ __launch_bounds__(512, 3) void attn_fused(
    const bf16_t* __restrict__ q, const bf16_t* __restrict__ k,
    const bf16_t* __restrict__ vt, bf16_t* o)
{
    __align__(16) __shared__ bf16_t sK[2][128 * 64];   // [key][dh], 8-chunk swizzle
    __align__(16) __shared__ bf16_t sVt[2][64 * 128];  // [dh][key-perm], 16-chunk swizzle

    const int t    = threadIdx.x;
    const int lane = t & 63;
    const int w    = t >> 6;                 // 0..7
    const int head = blockIdx.x;             // 0..63
    const int b    = head >> 4;
    const int h    = head & 15;
    const size_t base = (size_t)b * S_LEN * D_MODEL + (size_t)h * HEAD_DIM;
    const bf16_t* vth = vt + ((size_t)b * 1024 + h * 64) * 2048;  // [dh][s-perm]
    const int qt0  = blockIdx.y * 256;
    const int q4   = lane >> 4;
    const int l16  = lane & 15;

    bf16x8 qf[2][2];
#pragma unroll
    for (int mg = 0; mg < 2; mg++)
#pragma unroll
        for (int kk = 0; kk < 2; kk++)
            qf[mg][kk] = *(const bf16x8*)&q[base + (size_t)(qt0 + w * 32 + mg * 16 + l16) * D_MODEL + kk * 32 + q4 * 8];

    const f32x4 zero4 = {0.f, 0.f, 0.f, 0.f};
    f32x4 oacc[2][4];
#pragma unroll
    for (int mg = 0; mg < 2; mg++)
#pragma unroll
        for (int g = 0; g < 4; g++) oacc[mg][g] = zero4;
    f32x4 sacc[2] = {zero4, zero4};          // row sums via ones-MFMA

    bf16x8 ones;
#pragma unroll
    for (int j = 0; j < 8; j++) ones[j] = (bf16_t)1.0f;

    auto stage = [&](int bf, int kt) {
        const int key0 = kt * 128;
#pragma unroll
        for (int i = 0; i < 2; i++) {
            const int cid = i * 512 + t;           // 1024 16B chunks of K
            const int row = cid >> 3;
            const int cg  = (cid & 7) ^ (row & 7);
            async_copy16(&sK[bf][cid * 8], &k[base + (size_t)(key0 + row) * D_MODEL + cg * 8]);
        }
#pragma unroll
        for (int i = 0; i < 2; i++) {
            const int cid = i * 512 + t;           // 1024 16B chunks of V^T
            const int dh  = cid >> 4;
            const int cg  = (cid & 15) ^ (dh & 15);
            async_copy16(&sVt[bf][cid * 8], &vth[(size_t)dh * 2048 + key0 + cg * 8]);
        }
    };

    stage(0, 0);
    asm volatile("s_waitcnt vmcnt(0)" ::: "memory");
    __builtin_amdgcn_s_barrier();
    __builtin_amdgcn_sched_barrier(0);

    for (int kt = 0; kt < KVT; ++kt) {
        const int cur = kt & 1;
        if (kt < KVT - 1) stage(cur ^ 1, kt + 1);   // flies under compute

#pragma unroll
        for (int hh = 0; hh < 2; hh++) {
            // S^T = K @ Q^T : first k-slice reads zero4 as C (no acc copies)
            f32x4 sc[2][4];
            __builtin_amdgcn_s_setprio(1);
#pragma unroll
            for (int ngl = 0; ngl < 4; ngl++) {
                const int key = (hh * 4 + ngl) * 16 + l16;
                const bf16x8 kf0 = *(const bf16x8*)&sK[cur][key * 64 + ((q4) ^ (key & 7)) * 8];
                const bf16x8 kf1 = *(const bf16x8*)&sK[cur][key * 64 + ((4 + q4) ^ (key & 7)) * 8];
#pragma unroll
                for (int mg = 0; mg < 2; mg++) {
                    sc[mg][ngl] = __builtin_amdgcn_mfma_f32_16x16x32_bf16(kf0, qf[mg][0], zero4, 0, 0, 0);
                    sc[mg][ngl] = __builtin_amdgcn_mfma_f32_16x16x32_bf16(kf1, qf[mg][1], sc[mg][ngl], 0, 0, 0);
                }
            }
            __builtin_amdgcn_s_setprio(0);

            // softmax: p = 2^s (kb carries log2e); pack pairs straight into
            // PV A-fragments via v_cvt_pk_bf16_f32.
            bf16x8 pf[2][2];
#pragma unroll
            for (int mg = 0; mg < 2; mg++) {
#pragma unroll
                for (int ngl = 0; ngl < 4; ngl++)
#pragma unroll
                    for (int r = 0; r < 4; r++)
                        sc[mg][ngl][r] = exp2f(sc[mg][ngl][r]);
#pragma unroll
                for (int cl = 0; cl < 2; cl++) {
                    union { uint32_t u[4]; bf16x8 v; } pk;
#pragma unroll
                    for (int dw = 0; dw < 4; dw++) {
                        const int c = cl * 2 + (dw >> 1);
                        const int e = (dw & 1) * 2;
                        pk.u[dw] = cvt_pk_bf16(sc[mg][c][e], sc[mg][c][e + 1]);
                    }
                    pf[mg][cl] = pk.v;
                }
            }

            // PV + row-sum MFMAs (V^T stored in matching permuted k-order)
            __builtin_amdgcn_s_setprio(1);
#pragma unroll
            for (int cl = 0; cl < 2; cl++) {
                const int cb = (hh * 2 + cl) * 4;
#pragma unroll
                for (int g = 0; g < 4; g++) {
                    const int dh = g * 16 + l16;
                    const bf16x8 vf = *(const bf16x8*)&sVt[cur][dh * 128 + ((cb + q4) ^ l16) * 8];
#pragma unroll
                    for (int mg = 0; mg < 2; mg++)
                        oacc[mg][g] = __builtin_amdgcn_mfma_f32_16x16x32_bf16(pf[mg][cl], vf, oacc[mg][g], 0, 0, 0);
                }
#pragma unroll
                for (int mg = 0; mg < 2; mg++)
                    sacc[mg] = __builtin_amdgcn_mfma_f32_16x16x32_bf16(pf[mg][cl], ones, sacc[mg], 0, 0, 0);
            }
            __builtin_amdgcn_s_setprio(0);
        }

        asm volatile("s_waitcnt vmcnt(0)" ::: "memory");
        __builtin_amdgcn_s_barrier();
        __builtin_amdgcn_sched_barrier(0);
    }

    // normalize + store: sacc[mg][r] holds the full row sum for qrow q4*4+r
#pragma unroll
    for (int mg = 0; mg < 2; mg++)
#pragma unroll
        for (int r = 0; r < 4; r++) {
            const float inv = 1.0f / sacc[mg][r];
            const size_t rowoff = base + (size_t)(qt0 + w * 32 + mg * 16 + q4 * 4 + r) * D_MODEL;
#pragma unroll
            for (int g = 0; g < 4; g++)
                o[rowoff + g * 16 + l16] = (bf16_t)(oacc[mg][g][r] * inv);
        }
}

// ---------------------------------------------------------------------------
// Buffer plan (ws = 33.55 MB, d_out = 32 MiB fp32 output):
//   ws:    qb [0,16.78MB) | vb [16.78,33.55MB)
//   d_out: kb (bf16) [0,16MiB) | Wq/Wk/Wv bf16 [16,22.3MiB)
//   Wo-bf16 -> vb region (dead after attn). ob aliases qb.
// Order: convW(q,k,v) -> proj -> attn -> convW(o) -> out.
// ---------------------------------------------------------------------------
extern "C" void kernel_launch(void* const* d_in, const int* in_sizes, int n_in,
                              void* d_out, int out_size, void* d_ws, size_t ws_size,
                              hipStream_t stream) {
    const float* Q  = (const float*)d_in[0];
    const float* K  = (const float*)d_in[1];
    const float* V  = (const float*)d_in[2];
    const float* Wq = (const float*)d_in[3];
    const float* bq = (const float*)d_in[4];
    const float* Wk = (const float*)d_in[5];
    const float* bk = (const float*)d_in[6];
    const float* Wv = (const float*)d_in[7];
    const float* bv = (const float*)d_in[8];
    const float* Wo = (const float*)d_in[9];
    const float* bo = (const float*)d_in[10];
    float* out = (float*)d_out;

    bf16_t* qb  = (bf16_t*)d_ws;
    bf16_t* vb  = qb + (size_t)M_ROWS * D_MODEL;
    bf16_t* kb  = (bf16_t*)d_out;
    bf16_t* wqb = kb + (size_t)M_ROWS * D_MODEL;     // d_out + 16 MiB
    bf16_t* wkb = wqb + (size_t)D_MODEL * D_MODEL;
    bf16_t* wvb = wkb + (size_t)D_MODEL * D_MODEL;
    bf16_t* wob = vb;                                 // vb dead after attn
    bf16_t* ob  = qb;

    conv_w<<<dim3(512, 3), dim3(256), 0, stream>>>(Wq, Wk, Wv, wqb, wkb, wvb);
    gemm_proj<<<dim3(8, 64, 3), dim3(512), 0, stream>>>(Q, wqb, bq, K, wkb, bk, V, wvb, bv, qb, kb, vb);
    attn_fused<<<dim3(4 * N_HEADS, S_LEN / 256), dim3(512), 0, stream>>>(qb, kb, vb, ob);
    conv_w<<<dim3(512, 1), dim3(256), 0, stream>>>(Wo, Wo, Wo, wob, wob, wob);
    gemm_out<<<dim3(8, 64), dim3(256), 0, stream>>>(ob, wob, bo, out);
}

// Round 7
// 361.304 us; speedup vs baseline: 1.0593x; 1.0593x over previous
//
#include <hip/hip_runtime.h>
#include <hip/hip_bf16.h>
#include <stdint.h>
#include <stddef.h>

// ---------------------------------------------------------------------------
// MultiHeadAttention: q/k/v = X @ W.T + b ; flash-attn per head ; out @ Wo.T+bo
// FP32 in/out buffers; bf16 MFMA internally.
// B=4 S=2048 D=1024 H=16 Dh=64 -> M = B*S = 8192
// Round 12: r11's 8-wave proj REGRESSED (141 vs 121: occupancy up but per-wave
// MFMA-per-barrier halved -> fixed per-step costs dominate). Proj reverted to
// r10 exactly. Budget arithmetic exposed gemm_out at ~110us / 160 TF (it was
// never in top-5: that table is 5 iterations of the slowest kernel only).
// gemm_out now runs a 3-buffer 2-iteration-deep counted pipeline: stage(kt+2)
// issued per iter, vmcnt(4) waits only stage(kt) (stage(kt+1) stays in
// flight) -> every load has >=2 iterations (~500 cyc) of cover. LDS 48KB x3
// blocks = 144KB fits.
// attn / conv_w unchanged.
// ---------------------------------------------------------------------------

typedef __bf16 bf16_t;
typedef __bf16 bf16x4 __attribute__((ext_vector_type(4)));
typedef __bf16 bf16x8 __attribute__((ext_vector_type(8)));
typedef float f32x4 __attribute__((ext_vector_type(4)));

#define D_MODEL 1024
#define M_ROWS  8192
#define S_LEN   2048
#define N_HEADS 16
#define HEAD_DIM 64
#define GBK 32
#define NT (D_MODEL / GBK)   // 32 k-tiles

__device__ __forceinline__ void async_copy16(void* lds, const void* g) {
    __builtin_amdgcn_global_load_lds(
        (const __attribute__((address_space(1))) void*)g,
        (__attribute__((address_space(3))) void*)lds, 16, 0, 0);
}

__device__ __forceinline__ uint32_t cvt_pk_bf16(float lo, float hi) {
    uint32_t r;
    asm("v_cvt_pk_bf16_f32 %0, %1, %2" : "=v"(r) : "v"(lo), "v"(hi));
    return r;
}

// ---------------------------------------------------------------------------
// fp32 -> bf16 conversion (W matrices, 1M elems each). grid (512, nmat).
// ---------------------------------------------------------------------------
__global__ __launch_bounds__(256) void conv_w(
    const float* __restrict__ s0, const float* __restrict__ s1, const float* __restrict__ s2,
    bf16_t* __restrict__ d0, bf16_t* __restrict__ d1, bf16_t* __restrict__ d2)
{
    const float* s; bf16_t* d;
    if (blockIdx.y == 0)      { s = s0; d = d0; }
    else if (blockIdx.y == 1) { s = s1; d = d1; }
    else                      { s = s2; d = d2; }
    const int i = (blockIdx.x * 256 + threadIdx.x) * 8;
    const f32x4 a = *(const f32x4*)(s + i);
    const f32x4 b = *(const f32x4*)(s + i + 4);
    bf16x8 o;
#pragma unroll
    for (int j = 0; j < 4; j++) { o[j] = (bf16_t)a[j]; o[4 + j] = (bf16_t)b[j]; }
    *(bf16x8*)(d + i) = o;
}

// ---------------------------------------------------------------------------
// Projection GEMM (r10 version, measured 121us): C[m,n] = sum_k A[m,k]*W[n,k]
// + bias[n]. A fp32 (reg-staged, 2-deep, loads live across the barrier via
// vmcnt(4)); W bf16 (global_load_lds, staged under the MFMA cluster);
// bias fp32; C bf16. 128x128 tile, BK=32, 256 thr (4 waves, 2x2 of 64x64).
// Raw s_barrier + counted vmcnt per k-step. XCD-chunked swizzle.
// z==0 (Q): output scaled 0.125. z==1 (K): scaled log2e. z==2 (V): transposed
// per head [b][dh][s] with per-32-key permutation.
// ---------------------------------------------------------------------------
__global__ __launch_bounds__(256, 3) void gemm_proj(
    const float* __restrict__ A0, const bf16_t* __restrict__ W0, const float* __restrict__ b0,
    const float* __restrict__ A1, const bf16_t* __restrict__ W1, const float* __restrict__ b1,
    const float* __restrict__ A2, const bf16_t* __restrict__ W2, const float* __restrict__ b2,
    bf16_t* C0, bf16_t* C1, bf16_t* C2)
{
    const int lin = blockIdx.x + ((int)blockIdx.y << 3) + ((int)blockIdx.z << 9);
    const int nl  = (lin & 7) * 192 + (lin >> 3);          // bijective, 1536%8==0
    const int z   = nl >> 9;
    const int rem = nl & 511;
    const int bm0 = (rem >> 3) * 128;
    const int bn0 = (rem & 7) * 128;

    const float* A; const bf16_t* W; const float* bias; bf16_t* C;
    if (z == 0)      { A = A0; W = W0; bias = b0; C = C0; }
    else if (z == 1) { A = A1; W = W1; bias = b1; C = C1; }
    else             { A = A2; W = W2; bias = b2; C = C2; }
    const float cs = (z == 0) ? 0.125f : (z == 1) ? 1.4426950408889634f : 1.0f;

    __align__(16) __shared__ bf16_t sA[2][128 * 36];   // padded rows (72B stride)
    __align__(16) __shared__ bf16_t sW[2][128 * GBK];  // linear: async dest

    const int t    = threadIdx.x;
    const int lane = t & 63;
    const int w    = t >> 6;
    const int wm   = (w & 1) * 64;
    const int wn   = (w >> 1) * 64;
    const int q4   = lane >> 4;
    const int l16  = lane & 15;

    const int srow  = t >> 1;
    const int cbase = (t & 1) * 2;
    const float* aptr = &A[(size_t)(bm0 + srow) * D_MODEL + cbase * 8];

    // W staging: source chunk cg = cl ^ ((row>>1)&3)  (bank-conflict-free read)
    auto stageW = [&](int buf, int kt) {
#pragma unroll
        for (int i = 0; i < 2; i++) {
            const int cid = i * 256 + t;
            const int row = cid >> 2;
            const int cg  = (cid & 3) ^ ((row >> 1) & 3);
            async_copy16(&sW[buf][cid * 8],
                         &W[(size_t)(bn0 + row) * D_MODEL + kt * GBK + cg * 8]);
        }
    };
    // A LDS write: chunk c at slot c ^ (srow&3)  (72B row stride, read matches)
    auto writeA = [&](int buf, f32x4 (&ar)[4]) {
        bf16x8 abf[2];
#pragma unroll
        for (int c = 0; c < 4; c++)
#pragma unroll
            for (int j = 0; j < 4; j++)
                abf[c >> 1][(c & 1) * 4 + j] = (bf16_t)ar[c][j];
#pragma unroll
        for (int hb = 0; hb < 2; hb++) {
            const int slot = (cbase + hb) ^ (srow & 3);
            *(bf16x8*)&sA[buf][srow * 36 + slot * 8] = abf[hb];
        }
    };

    // preamble: W(0) async; A(0)->arA, A(1)->arB; sA[0] <- arA; publish.
    stageW(0, 0);
    f32x4 arA[4], arB[4];
#pragma unroll
    for (int c = 0; c < 4; c++) arA[c] = *(const f32x4*)(aptr + c * 4);
#pragma unroll
    for (int c = 0; c < 4; c++) arB[c] = *(const f32x4*)(aptr + GBK + c * 4);
    writeA(0, arA);    // compiler waits arA (vmcnt(4): arB stays in flight)
    asm volatile("s_waitcnt vmcnt(4) lgkmcnt(0)" ::: "memory");  // W(0) home too
    __builtin_amdgcn_s_barrier();
    __builtin_amdgcn_sched_barrier(0);

    f32x4 acc[4][4];
    const f32x4 zero4 = {0.f, 0.f, 0.f, 0.f};
#pragma unroll
    for (int i = 0; i < 4; i++)
#pragma unroll
        for (int j = 0; j < 4; j++) acc[i][j] = zero4;

    // body(kt): compute buf; stage W(kt+1)+A(kt+1)->LDS buf^1; load A(kt+2).
    auto body = [&](int kt, int buf, f32x4 (&arCur)[4], f32x4 (&arNext)[4]) {
        if (kt + 1 < NT) stageW(buf ^ 1, kt + 1);            // 2 vm (oldest)
        if (kt + 2 < NT) {
            const float* ap = aptr + (size_t)(kt + 2) * GBK;
#pragma unroll
            for (int c = 0; c < 4; c++) arNext[c] = *(const f32x4*)(ap + c * 4);
        }

        bf16x8 af[4], bfr[4];
#pragma unroll
        for (int i = 0; i < 4; i++) {
            const int m = wm + i * 16 + l16;
            af[i]  = *(const bf16x8*)&sA[buf][m * 36 + (q4 ^ (m & 3)) * 8];
            const int n = wn + i * 16 + l16;
            bfr[i] = *(const bf16x8*)&sW[buf][n * GBK + (q4 ^ ((n >> 1) & 3)) * 8];
        }
#pragma unroll
        for (int i = 0; i < 4; i++)
#pragma unroll
            for (int j = 0; j < 4; j++)
                acc[i][j] = __builtin_amdgcn_mfma_f32_16x16x32_bf16(af[i], bfr[j], acc[i][j], 0, 0, 0);

        // A(kt+1) -> sA[buf^1] AFTER the MFMAs (arCur's vmcnt lands late)
        __builtin_amdgcn_sched_barrier(0);
        if (kt + 1 < NT) writeA(buf ^ 1, arCur);
        // W(kt+1) + sA writes must be home; arNext (4 loads) stays in flight.
        if (kt + 2 < NT) asm volatile("s_waitcnt vmcnt(4) lgkmcnt(0)" ::: "memory");
        else             asm volatile("s_waitcnt vmcnt(0) lgkmcnt(0)" ::: "memory");
        __builtin_amdgcn_s_barrier();
        __builtin_amdgcn_sched_barrier(0);
    };

    for (int kt = 0; kt < NT; kt += 2) {
        body(kt,     0, arB, arA);
        body(kt + 1, 1, arA, arB);
    }

    if (z != 2) {
#pragma unroll
        for (int j = 0; j < 4; j++) {
            const int col = bn0 + wn + j * 16 + l16;
            const float bj = bias[col];
#pragma unroll
            for (int i = 0; i < 4; i++) {
                const int rowb = bm0 + wm + i * 16 + q4 * 4;
#pragma unroll
                for (int r = 0; r < 4; r++)
                    C[(size_t)(rowb + r) * D_MODEL + col] = (bf16_t)((acc[i][j][r] + bj) * cs);
            }
        }
    } else {
        const int bb = bm0 >> 11;          // batch (tile never straddles)
        const int sbase = (bm0 & 2047) + wm;
#pragma unroll
        for (int j = 0; j < 4; j++) {
            const int col = bn0 + wn + j * 16 + l16;
            const float bj = bias[col];
            bf16_t* ct = C + ((size_t)bb * 1024 + col) * 2048;
#pragma unroll
            for (int i = 0; i < 4; i++) {
                const int s0 = sbase + i * 16 + q4 * 4;
                // permute: c*32 + g*16 + p*4  ->  c*32 + p*8 + g*4
                const int s0p = (s0 & ~31) | (((s0 >> 2) & 3) << 3) | (((s0 >> 4) & 1) << 2);
                bf16x4 v4;
#pragma unroll
                for (int r = 0; r < 4; r++) v4[r] = (bf16_t)(acc[i][j][r] + bj);
                *(bf16x4*)&ct[s0p] = v4;
            }
        }
    }
}

// ---------------------------------------------------------------------------
// Output GEMM: A bf16 (attention out), W bf16 (pre-converted Wo), bias fp32,
// C fp32 (d_out). 3-buffer 2-deep counted pipeline: stage(kt+2) issued each
// iter; vmcnt(4) at the top waits only stage(kt) (stage(kt+1) stays in
// flight) -> >=2 iterations of latency cover per load. Raw s_barrier.
// XCD-chunked swizzle; ((row>>1)&3) conflict-free LDS swizzle.
// ---------------------------------------------------------------------------
__global__ __launch_bounds__(256, 3) void gemm_out(
    const bf16_t* __restrict__ A, const bf16_t* __restrict__ W,
    const float* __restrict__ bias, float* __restrict__ C)
{
    const int lin = blockIdx.x + ((int)blockIdx.y << 3);
    const int nl  = (lin & 7) * 64 + (lin >> 3);           // bijective, 512%8==0
    const int bm0 = (nl >> 3) * 128;
    const int bn0 = (nl & 7) * 128;

    __align__(16) __shared__ bf16_t sA[3][128 * GBK];      // 24 KB
    __align__(16) __shared__ bf16_t sW[3][128 * GBK];      // 24 KB

    const int t    = threadIdx.x;
    const int lane = t & 63;
    const int w    = t >> 6;
    const int wm   = (w & 1) * 64;
    const int wn   = (w >> 1) * 64;
    const int q4   = lane >> 4;
    const int l16  = lane & 15;

    auto stage = [&](int buf, int kt) {
#pragma unroll
        for (int i = 0; i < 2; i++) {
            const int cid = i * 256 + t;
            const int row = cid >> 2;
            const int cg  = (cid & 3) ^ ((row >> 1) & 3);
            async_copy16(&sA[buf][cid * 8],
                         &A[(size_t)(bm0 + row) * D_MODEL + kt * GBK + cg * 8]);
            async_copy16(&sW[buf][cid * 8],
                         &W[(size_t)(bn0 + row) * D_MODEL + kt * GBK + cg * 8]);
        }
    };

    // prologue: two tiles in flight
    stage(0, 0);
    stage(1, 1);

    f32x4 acc[4][4];
    const f32x4 zero4 = {0.f, 0.f, 0.f, 0.f};
#pragma unroll
    for (int i = 0; i < 4; i++)
#pragma unroll
        for (int j = 0; j < 4; j++) acc[i][j] = zero4;

    for (int kt = 0; kt < NT; ++kt) {
        const int buf = kt % 3;
        // wait stage(kt) home; stage(kt+1)'s 4 ops may stay outstanding
        if (kt + 1 < NT) asm volatile("s_waitcnt vmcnt(4)" ::: "memory");
        else             asm volatile("s_waitcnt vmcnt(0)" ::: "memory");
        __builtin_amdgcn_s_barrier();
        __builtin_amdgcn_sched_barrier(0);
        if (kt + 2 < NT) stage((kt + 2) % 3, kt + 2);   // 2 iters of cover

        bf16x8 af[4], bfr[4];
#pragma unroll
        for (int i = 0; i < 4; i++) {
            const int m = wm + i * 16 + l16;
            af[i]  = *(const bf16x8*)&sA[buf][m * GBK + (q4 ^ ((m >> 1) & 3)) * 8];
            const int n = wn + i * 16 + l16;
            bfr[i] = *(const bf16x8*)&sW[buf][n * GBK + (q4 ^ ((n >> 1) & 3)) * 8];
        }
#pragma unroll
        for (int i = 0; i < 4; i++)
#pragma unroll
            for (int j = 0; j < 4; j++)
                acc[i][j] = __builtin_amdgcn_mfma_f32_16x16x32_bf16(af[i], bfr[j], acc[i][j], 0, 0, 0);
    }

#pragma unroll
    for (int j = 0; j < 4; j++) {
        const int col = bn0 + wn + j * 16 + l16;
        const float bj = bias[col];
#pragma unroll
        for (int i = 0; i < 4; i++) {
            const int rowb = bm0 + wm + i * 16 + q4 * 4;
#pragma unroll
            for (int r = 0; r < 4; r++)
                C[(size_t)(rowb + r) * D_MODEL + col] = acc[i][j][r] + bj;
        }
    }
}

// ---------------------------------------------------------------------------
// Flash attention (unchanged). grid = (B*H=64, S/256=8), 512 thr = 8 waves.
// Double-buffered K / permuted V^T, one raw s_barrier + vmcnt(0) per tile.
// Swapped QK^T (qb pre-scaled 0.125, kb pre-scaled log2e); P via
// v_cvt_pk_bf16_f32 straight into PV A-fragments; row sums via ones-MFMA.
// ---------------------------------------------------------------------------
#define KVT (S_LEN / 128)   // 16 key tiles

__global__ __launch_bounds__(512, 3) void attn_fused(
    const bf16_t* __restrict__ q, const bf16_t* __restrict__ k,
    const bf16_t* __restrict__ vt, bf16_t* o)
{
    __align__(16) __shared__ bf16_t sK[2][128 * 64];   // [key][dh], 8-chunk swizzle
    __align__(16) __shared__ bf16_t sVt[2][64 * 128];  // [dh][key-perm], 16-chunk swizzle

    const int t    = threadIdx.x;
    const int lane = t & 63;
    const int w    = t >> 6;                 // 0..7
    const int head = blockIdx.x;             // 0..63
    const int b    = head >> 4;
    const int h    = head & 15;
    const size_t base = (size_t)b * S_LEN * D_MODEL + (size_t)h * HEAD_DIM;
    const bf16_t* vth = vt + ((size_t)b * 1024 + h * 64) * 2048;  // [dh][s-perm]
    const int qt0  = blockIdx.y * 256;
    const int q4   = lane >> 4;
    const int l16  = lane & 15;

    bf16x8 qf[2][2];
#pragma unroll
    for (int mg = 0; mg < 2; mg++)
#pragma unroll
        for (int kk = 0; kk < 2; kk++)
            qf[mg][kk] = *(const bf16x8*)&q[base + (size_t)(qt0 + w * 32 + mg * 16 + l16) * D_MODEL + kk * 32 + q4 * 8];

    const f32x4 zero4 = {0.f, 0.f, 0.f, 0.f};
    f32x4 oacc[2][4];
#pragma unroll
    for (int mg = 0; mg < 2; mg++)
#pragma unroll
        for (int g = 0; g < 4; g++) oacc[mg][g] = zero4;
    f32x4 sacc[2] = {zero4, zero4};          // row sums via ones-MFMA

    bf16x8 ones;
#pragma unroll
    for (int j = 0; j < 8; j++) ones[j] = (bf16_t)1.0f;

    auto stage = [&](int bf, int kt) {
        const int key0 = kt * 128;
#pragma unroll
        for (int i = 0; i < 2; i++) {
            const int cid = i * 512 + t;           // 1024 16B chunks of K
            const int row = cid >> 3;
            const int cg  = (cid & 7) ^ (row & 7);
            async_copy16(&sK[bf][cid * 8], &k[base + (size_t)(key0 + row) * D_MODEL + cg * 8]);
        }
#pragma unroll
        for (int i = 0; i < 2; i++) {
            const int cid = i * 512 + t;           // 1024 16B chunks of V^T
            const int dh  = cid >> 4;
            const int cg  = (cid & 15) ^ (dh & 15);
            async_copy16(&sVt[bf][cid * 8], &vth[(size_t)dh * 2048 + key0 + cg * 8]);
        }
    };

    stage(0, 0);
    asm volatile("s_waitcnt vmcnt(0)" ::: "memory");
    __builtin_amdgcn_s_barrier();
    __builtin_amdgcn_sched_barrier(0);

    for (int kt = 0; kt < KVT; ++kt) {
        const int cur = kt & 1;
        if (kt < KVT - 1) stage(cur ^ 1, kt + 1);   // flies under compute

#pragma unroll
        for (int hh = 0; hh < 2; hh++) {
            // S^T = K @ Q^T : first k-slice reads zero4 as C (no acc copies)
            f32x4 sc[2][4];
            __builtin_amdgcn_s_setprio(1);
#pragma unroll
            for (int ngl = 0; ngl < 4; ngl++) {
                const int key = (hh * 4 + ngl) * 16 + l16;
                const bf16x8 kf0 = *(const bf16x8*)&sK[cur][key * 64 + ((q4) ^ (key & 7)) * 8];
                const bf16x8 kf1 = *(const bf16x8*)&sK[cur][key * 64 + ((4 + q4) ^ (key & 7)) * 8];
#pragma unroll
                for (int mg = 0; mg < 2; mg++) {
                    sc[mg][ngl] = __builtin_amdgcn_mfma_f32_16x16x32_bf16(kf0, qf[mg][0], zero4, 0, 0, 0);
                    sc[mg][ngl] = __builtin_amdgcn_mfma_f32_16x16x32_bf16(kf1, qf[mg][1], sc[mg][ngl], 0, 0, 0);
                }
            }
            __builtin_amdgcn_s_setprio(0);

            // softmax: p = 2^s (kb carries log2e); pack pairs straight into
            // PV A-fragments via v_cvt_pk_bf16_f32.
            bf16x8 pf[2][2];
#pragma unroll
            for (int mg = 0; mg < 2; mg++) {
#pragma unroll
                for (int ngl = 0; ngl < 4; ngl++)
#pragma unroll
                    for (int r = 0; r < 4; r++)
                        sc[mg][ngl][r] = exp2f(sc[mg][ngl][r]);
#pragma unroll
                for (int cl = 0; cl < 2; cl++) {
                    union { uint32_t u[4]; bf16x8 v; } pk;
#pragma unroll
                    for (int dw = 0; dw < 4; dw++) {
                        const int c = cl * 2 + (dw >> 1);
                        const int e = (dw & 1) * 2;
                        pk.u[dw] = cvt_pk_bf16(sc[mg][c][e], sc[mg][c][e + 1]);
                    }
                    pf[mg][cl] = pk.v;
                }
            }

            // PV + row-sum MFMAs (V^T stored in matching permuted k-order)
            __builtin_amdgcn_s_setprio(1);
#pragma unroll
            for (int cl = 0; cl < 2; cl++) {
                const int cb = (hh * 2 + cl) * 4;
#pragma unroll
                for (int g = 0; g < 4; g++) {
                    const int dh = g * 16 + l16;
                    const bf16x8 vf = *(const bf16x8*)&sVt[cur][dh * 128 + ((cb + q4) ^ l16) * 8];
#pragma unroll
                    for (int mg = 0; mg < 2; mg++)
                        oacc[mg][g] = __builtin_amdgcn_mfma_f32_16x16x32_bf16(pf[mg][cl], vf, oacc[mg][g], 0, 0, 0);
                }
#pragma unroll
                for (int mg = 0; mg < 2; mg++)
                    sacc[mg] = __builtin_amdgcn_mfma_f32_16x16x32_bf16(pf[mg][cl], ones, sacc[mg], 0, 0, 0);
            }
            __builtin_amdgcn_s_setprio(0);
        }

        asm volatile("s_waitcnt vmcnt(0)" ::: "memory");
        __builtin_amdgcn_s_barrier();
        __builtin_amdgcn_sched_barrier(0);
    }

    // normalize + store: sacc[mg][r] holds the full row sum for qrow q4*4+r
#pragma unroll
    for (int mg = 0; mg < 2; mg++)
#pragma unroll
        for (int r = 0; r < 4; r++) {
            const float inv = 1.0f / sacc[mg][r];
            const size_t rowoff = base + (size_t)(qt0 + w * 32 + mg * 16 + q4 * 4 + r) * D_MODEL;
#pragma unroll
            for (int g = 0; g < 4; g++)
                o[rowoff + g * 16 + l16] = (bf16_t)(oacc[mg][g][r] * inv);
        }
}

// ---------------------------------------------------------------------------
// Buffer plan (ws = 33.55 MB, d_out = 32 MiB fp32 output):
//   ws:    qb [0,16.78MB) | vb [16.78,33.55MB)
//   d_out: kb (bf16) [0,16MiB) | Wq/Wk/Wv bf16 [16,22.3MiB)
//   Wo-bf16 -> vb region (dead after attn). ob aliases qb.
// Order: convW(q,k,v) -> proj -> attn -> convW(o) -> out.
// ---------------------------------------------------------------------------
extern "C" void kernel_launch(void* const* d_in, const int* in_sizes, int n_in,
                              void* d_out, int out_size, void* d_ws, size_t ws_size,
                              hipStream_t stream) {
    const float* Q  = (const float*)d_in[0];
    const float* K  = (const float*)d_in[1];
    const float* V  = (const float*)d_in[2];
    const float* Wq = (const float*)d_in[3];
    const float* bq = (const float*)d_in[4];
    const float* Wk = (const float*)d_in[5];
    const float* bk = (const float*)d_in[6];
    const float* Wv = (const float*)d_in[7];
    const float* bv = (const float*)d_in[8];
    const float* Wo = (const float*)d_in[9];
    const float* bo = (const float*)d_in[10];
    float* out = (float*)d_out;

    bf16_t* qb  = (bf16_t*)d_ws;
    bf16_t* vb  = qb + (size_t)M_ROWS * D_MODEL;
    bf16_t* kb  = (bf16_t*)d_out;
    bf16_t* wqb = kb + (size_t)M_ROWS * D_MODEL;     // d_out + 16 MiB
    bf16_t* wkb = wqb + (size_t)D_MODEL * D_MODEL;
    bf16_t* wvb = wkb + (size_t)D_MODEL * D_MODEL;
    bf16_t* wob = vb;                                 // vb dead after attn
    bf16_t* ob  = qb;

    conv_w<<<dim3(512, 3), dim3(256), 0, stream>>>(Wq, Wk, Wv, wqb, wkb, wvb);
    gemm_proj<<<dim3(8, 64, 3), dim3(256), 0, stream>>>(Q, wqb, bq, K, wkb, bk, V, wvb, bv, qb, kb, vb);
    attn_fused<<<dim3(4 * N_HEADS, S_LEN / 256), dim3(512), 0, stream>>>(qb, kb, vb, ob);
    conv_w<<<dim3(512, 1), dim3(256), 0, stream>>>(Wo, Wo, Wo, wob, wob, wob);
    gemm_out<<<dim3(8, 64), dim3(256), 0, stream>>>(ob, wob, bo, out);
}